// Round 20
// baseline (129.774 us; speedup 1.0000x reference)
//
#include <hip/hip_runtime.h>

#define B 8
#define N 20000
#define M 256
#define I 64
#define O 64
#define MI (M * I)          // 16384
#define KT 32               // n-rows per MFMA K-tile (stage1)
#define SSS 264             // stage3 S^T LDS row stride (u16): 528 B = 33*16
#define MSW(m) ((m) ^ (((m) >> 3) & 7))   // r12-verified conflict-free cell swizzle

typedef __attribute__((ext_vector_type(8))) short   bf16x8;   // 8 bf16 (4 VGPR)
typedef __attribute__((ext_vector_type(4))) float   f32x4;    // MFMA acc
typedef __attribute__((ext_vector_type(4))) unsigned int uint4v;

// fp32 pair -> packed bf16 (RNE), one VALU op (no builtin on gfx950 -> asm).
__device__ __forceinline__ unsigned pk2bf(float lo, float hi) {
    unsigned r;
    asm("v_cvt_pk_bf16_f32 %0, %1, %2" : "=v"(r) : "v"(lo), "v"(hi));
    return r;
}

__device__ __forceinline__ unsigned short f2bf(float v) {
    unsigned a = __float_as_uint(v);
    return (unsigned short)((a + 0x7fffu + ((a >> 16) & 1u)) >> 16);
}

// ---------------- Stage 1 (MFMA): partial[s][b][m][i] = sum_n D[b,n,m]*x[b,n,i]
// r19 post-mortem: 1-wave blocks but grid (2016) capped residency at ~6-8
// waves/CU; per-step compute phase ~250 cyc vs ~900 cyc HBM latency needs
// ~15 waves/CU to cover. THIS ROUND: split=125 (chunk=160=5*KT exactly, no
// tail), grid 125*8*4 = 4000 single-wave blocks ~ 15.6 waves/CU. Everything
// else identical to r19 (wave-autonomous, zero barriers, conflicts=0).
__global__ __launch_bounds__(64) void stage1(const float* __restrict__ Dg,
                                             const float* __restrict__ xg,
                                             float* __restrict__ partial,
                                             int chunk) {
    const int b = blockIdx.y, s = blockIdx.x, w = blockIdx.z;
    const int n0 = s * chunk;
    const int nend = min(n0 + chunk, N);
    const int lane = threadIdx.x;     // 0..63
    const int lg = lane >> 4;         // lane-group = octet index
    const int l15 = lane & 15;
    const bool interior = (n0 + chunk) <= N;   // uniform (always true at 125x160)

    __shared__ unsigned short wD[4 * 64 * 8];   // 4 KB: cell (octet, m_loc)
    __shared__ unsigned short wX[4 * 64 * 8];   // 4 KB: cell (octet, i)

    f32x4 acc[4][4];
#pragma unroll
    for (int a = 0; a < 4; ++a)
#pragma unroll
        for (int v = 0; v < 4; ++v) acc[a][v] = (f32x4){0.f, 0.f, 0.f, 0.f};

    const float* Db = Dg + (size_t)b * N * M + w * 64;   // wave's m-col base
    const float* xb = xg + (size_t)b * N * I;

    const int steps = (nend > n0) ? (nend - n0 + KT - 1) / KT : 0;

    float4 dreg[8];   // D rows nb+8*lg+q, cols w*64+4*l15..+3  (octet lg)
    float4 xreg[8];   // x rows nb+8*lg+q, cols 4*l15..+3

    auto load_fast = [&](int nbase) {
        const float* dp = &Db[(size_t)(nbase + 8 * lg) * M + 4 * l15];
        const float* xp = &xb[(size_t)(nbase + 8 * lg) * I + 4 * l15];
#pragma unroll
        for (int q = 0; q < 8; ++q) {
            dreg[q] = *(const float4*)(dp + (size_t)q * M);
            xreg[q] = *(const float4*)(xp + (size_t)q * I);
        }
    };
    auto load_clamped = [&](int nbase) {
#pragma unroll
        for (int q = 0; q < 8; ++q) {
            const int nc = min(nbase + 8 * lg + q, N - 1);
            dreg[q] = *(const float4*)&Db[(size_t)nc * M + 4 * l15];
            xreg[q] = *(const float4*)&xb[(size_t)nc * I + 4 * l15];
        }
    };

    if (steps > 0) {
        if (interior) load_fast(n0); else load_clamped(n0);

        for (int t = 0; t < steps; ++t) {
            const int nb = n0 + t * KT;
            if (!interior) {   // tail blocks only: zero rows >= nend
#pragma unroll
                for (int q = 0; q < 8; ++q)
                    if (nb + 8 * lg + q >= nend) {
                        dreg[q] = make_float4(0.f, 0.f, 0.f, 0.f);
                        xreg[q] = make_float4(0.f, 0.f, 0.f, 0.f);
                    }
            }
            // ---- pack + LDS write: 4 D cells + 4 x cells (octet lg)
#pragma unroll
            for (int j = 0; j < 4; ++j) {
                uint4v cd, cx;
#pragma unroll
                for (int e = 0; e < 4; ++e) {
                    cd[e] = pk2bf(((const float*)&dreg[2 * e])[j],
                                  ((const float*)&dreg[2 * e + 1])[j]);
                    cx[e] = pk2bf(((const float*)&xreg[2 * e])[j],
                                  ((const float*)&xreg[2 * e + 1])[j]);
                }
                const int c = MSW(4 * l15 + j);
                *(uint4v*)&wD[((size_t)lg * 64 + c) * 8] = cd;
                *(uint4v*)&wX[((size_t)lg * 64 + c) * 8] = cx;
            }
            // ---- issue next step's loads: stay in flight across the MFMA
            // phase (no barriers in this kernel -> no vmcnt(0) drain points)
            if (t + 1 < steps) {
                if (interior) load_fast(nb + KT); else load_clamped(nb + KT);
            }
            // ---- fragments + MFMA (within-wave LDS RAW: lgkmcnt only)
            bf16x8 bfr[4];
#pragma unroll
            for (int v = 0; v < 4; ++v)
                bfr[v] = *(const bf16x8*)&wX[((size_t)lg * 64 + MSW(v * 16 + l15)) * 8];
#pragma unroll
            for (int sm = 0; sm < 4; ++sm) {
                bf16x8 afr = *(const bf16x8*)&wD[((size_t)lg * 64 + MSW(sm * 16 + l15)) * 8];
#pragma unroll
                for (int v = 0; v < 4; ++v)
                    acc[sm][v] = __builtin_amdgcn_mfma_f32_16x16x32_bf16(
                        afr, bfr[v], acc[sm][v], 0, 0, 0);
            }
        }
    }

    // ---- store partial tile in natural [m][i] layout
    // C-map (m89, HW-verified): col = lane&15 (i), row = (lane>>4)*4 + r (m)
    float* p = partial + ((size_t)s * B + b) * MI;
#pragma unroll
    for (int sm = 0; sm < 4; ++sm)
#pragma unroll
        for (int v = 0; v < 4; ++v)
#pragma unroll
            for (int r = 0; r < 4; ++r) {
                const int m = w * 64 + sm * 16 + ((lane >> 4) << 2) + r;
                const int i = v * 16 + (lane & 15);
                p[m * I + i] = acc[sm][v][r];
            }
}

// ---------------- Reduce: dtx[b][j] = sum_s partial[s][b][j]
__global__ __launch_bounds__(256) void reduce_partials(const float* __restrict__ partial,
                                                       float* __restrict__ dtx,
                                                       int nsplit) {
    const int bb = blockIdx.y;
    const int j = blockIdx.x * 256 + threadIdx.x;
    const float* p = partial + (size_t)bb * MI + j;
    float sum = 0.f;
#pragma unroll 4
    for (int s = 0; s < nsplit; ++s)
        sum += p[(size_t)s * B * MI];
    dtx[(size_t)bb * MI + j] = sum;
}

// ---------------- Stage 2: ST[b][o][m] = bf16( (1/16) sum_i coeff[o][i][m]*dtx[b][m][i] )
__global__ __launch_bounds__(256) void stage2(const float* __restrict__ coeff,
                                              const float* __restrict__ dtx,
                                              unsigned short* __restrict__ ST) {
    const int g = blockIdx.x * 256 + threadIdx.x;
    const int b = g >> 14;            // O*M = 16384
    const int rem = g & 16383;
    const int o = rem >> 8;
    const int m = rem & 255;
    const float* dt = dtx + (size_t)b * MI + (size_t)m * I;
    const float* cf = coeff + (size_t)o * I * M + m;
    float acc = 0.f;
#pragma unroll 8
    for (int i = 0; i < I; ++i)
        acc = fmaf(cf[(size_t)i * M], dt[i], acc);
    ST[((size_t)b * O + o) * M + m] = f2bf(acc * 0.0625f);   // 1/sqrt(256)
}

// ---------------- Stage 3 (MFMA): out[b][n][o] = sum_m D[b,n,m] * S[b,m,o]
__global__ __launch_bounds__(256) void stage3(const float* __restrict__ Dg,
                                              const unsigned short* __restrict__ STg,
                                              float* __restrict__ outg) {
    const int b = blockIdx.y;
    const int n0 = blockIdx.x * 256;
    const int tid = threadIdx.x;
    const int lane = tid & 63;
    const int w = tid >> 6;

    __shared__ unsigned short sS[64 * SSS];   // 33 KB

    {
        const int o = tid >> 2, seg = (tid & 3) * 64;
        const unsigned short* src = STg + ((size_t)b * O + o) * M + seg;
        unsigned short* dst = &sS[o * SSS + seg];
#pragma unroll
        for (int c = 0; c < 8; ++c)
            *(uint4v*)&dst[c * 8] = *(const uint4v*)&src[c * 8];
    }

    f32x4 acc[4][4];
#pragma unroll
    for (int a = 0; a < 4; ++a)
#pragma unroll
        for (int v = 0; v < 4; ++v) acc[a][v] = (f32x4){0.f, 0.f, 0.f, 0.f};

    __syncthreads();

    const float* Db = Dg + (size_t)b * N * M;
    const int k8 = (lane >> 4) << 3;

#pragma unroll 1
    for (int ks = 0; ks < 8; ++ks) {
        const int kb = ks * 32 + k8;
        bf16x8 bfr[4];
#pragma unroll
        for (int v = 0; v < 4; ++v)
            bfr[v] = *(const bf16x8*)&sS[(v * 16 + (lane & 15)) * SSS + kb];
#pragma unroll
        for (int sn = 0; sn < 4; ++sn) {
            int n = n0 + w * 64 + sn * 16 + (lane & 15);
            n = min(n, N - 1);                       // tail clamp (stores guarded)
            const float* ap = Db + (size_t)n * M + kb;
            const float4 f0 = *(const float4*)ap;
            const float4 f1 = *(const float4*)(ap + 4);
            uint4v pk = {pk2bf(f0.x, f0.y), pk2bf(f0.z, f0.w),
                         pk2bf(f1.x, f1.y), pk2bf(f1.z, f1.w)};
            bf16x8 afr = __builtin_bit_cast(bf16x8, pk);
#pragma unroll
            for (int v = 0; v < 4; ++v)
                acc[sn][v] = __builtin_amdgcn_mfma_f32_16x16x32_bf16(
                    afr, bfr[v], acc[sn][v], 0, 0, 0);
        }
    }

#pragma unroll
    for (int sn = 0; sn < 4; ++sn)
#pragma unroll
        for (int v = 0; v < 4; ++v)
#pragma unroll
            for (int r = 0; r < 4; ++r) {
                const int n = n0 + w * 64 + sn * 16 + ((lane >> 4) << 2) + r;
                if (n < N)
                    outg[((size_t)b * N + n) * O + v * 16 + (lane & 15)] = acc[sn][v][r];
            }
}

extern "C" void kernel_launch(void* const* d_in, const int* in_sizes, int n_in,
                              void* d_out, int out_size, void* d_ws, size_t ws_size,
                              hipStream_t stream) {
    const float* Dg    = (const float*)d_in[0];
    const float* xg    = (const float*)d_in[1];
    const float* coeff = (const float*)d_in[2];
    float* outg = (float*)d_out;

    float* base = (float*)d_ws;
    float* dtx = base;                                   // B*MI floats   (512 KB)
    unsigned short* ST = (unsigned short*)(base + B * MI);  // B*O*M bf16 (256 KB)
    float* partial = base + B * MI + B * MI / 2;         // split * B*MI floats

    // split-K from workspace; cap 125 -> chunk 160 = 5*KT exactly (no tail),
    // grid 125*8*4 = 4000 single-wave blocks ~ 15.6 waves/CU.
    const size_t fixed = (size_t)B * MI * 4 + (size_t)B * MI * 2;
    const size_t per   = (size_t)B * MI * sizeof(float);
    int cap = 1;
    if (ws_size > fixed) {
        size_t c = (ws_size - fixed) / per;
        cap = (int)(c < 1 ? 1 : (c > 125 ? 125 : c));
    }
    int chunk = (((N + cap - 1) / cap) + KT - 1) & ~(KT - 1);
    int split = (N + chunk - 1) / chunk;   // blocks actually launched

    stage1<<<dim3(split, B, 4), 64, 0, stream>>>(Dg, xg, partial, chunk);
    reduce_partials<<<dim3(MI / 256, B), 256, 0, stream>>>(partial, dtx, split);
    stage2<<<dim3((B * O * M) / 256), 256, 0, stream>>>(coeff, dtx, ST);
    stage3<<<dim3((N + 255) / 256, B), 256, 0, stream>>>(Dg, ST, outg);
}

// Round 21
// 91.093 us; speedup vs baseline: 1.4246x; 1.4246x over previous
//
#include <hip/hip_runtime.h>

#define B 8
#define N 20000
#define M 256
#define I 64
#define O 64
#define MI (M * I)          // 16384
#define KT 32               // n-rows per MFMA K-tile (stage1)
#define PW (MI / 2)         // 8192 packed u32 words per partial slot
#define SSS 264             // stage3 S^T LDS row stride (u16): 528 B = 33*16
#define MSW(m) ((m) ^ (((m) >> 3) & 7))   // r12-verified conflict-free cell swizzle

typedef __attribute__((ext_vector_type(8))) short   bf16x8;   // 8 bf16 (4 VGPR)
typedef __attribute__((ext_vector_type(4))) float   f32x4;    // MFMA acc
typedef __attribute__((ext_vector_type(4))) unsigned int uint4v;

// fp32 pair -> packed bf16 (RNE): lo -> bits[15:0], hi -> bits[31:16].
__device__ __forceinline__ unsigned pk2bf(float lo, float hi) {
    unsigned r;
    asm("v_cvt_pk_bf16_f32 %0, %1, %2" : "=v"(r) : "v"(lo), "v"(hi));
    return r;
}

__device__ __forceinline__ unsigned short f2bf(float v) {
    unsigned a = __float_as_uint(v);
    return (unsigned short)((a + 0x7fffu + ((a >> 16) & 1u)) >> 16);
}

// async global->LDS, 16B per lane, LDS dest = uniform base + lane*16 (HW rule).
__device__ __forceinline__ void gload16(const float* src, float* lds) {
    __builtin_amdgcn_global_load_lds(
        (const __attribute__((address_space(1))) void*)src,
        (__attribute__((address_space(3))) void*)lds, 16, 0, 0);
}

// ---------------- Stage 1 (MFMA): partial[s][b] += D^T x over chunk rows.
// r17 structure (best known: DMA-ring D staging, wave-private, no barriers).
// r21 change: partials stored as PACKED BF16 u32 words (halves partial
// traffic 32->16 MB; reduce decodes). Word c = sm*8+v*2+rp holds
// (acc[sm][v][2rp], acc[sm][v][2rp+1]) = dtx rows m0,m0+1 at col i.
__global__ __launch_bounds__(256) void stage1(const float* __restrict__ Dg,
                                              const float* __restrict__ xg,
                                              unsigned* __restrict__ partial,
                                              int chunk) {
    const int b = blockIdx.y, s = blockIdx.x;
    const int n0 = s * chunk;
    const int nend = min(n0 + chunk, N);
    const int tid = threadIdx.x;
    const int lane = tid & 63;
    const int w = tid >> 6;
    const int lg = lane >> 4;
    const int l15 = lane & 15;

    __shared__ float sD[4][2][KT * 64];            // 4 waves x 2 slots x 8 KB
    __shared__ unsigned short sX[4][4 * 64 * 8];   // 16 KB

    f32x4 acc[4][4];
#pragma unroll
    for (int a = 0; a < 4; ++a)
#pragma unroll
        for (int v = 0; v < 4; ++v) acc[a][v] = (f32x4){0.f, 0.f, 0.f, 0.f};

    const float* Db = Dg + (size_t)b * N * M;
    const float* xb = xg + (size_t)b * N * I;

    const int steps = (nend > n0) ? (nend - n0) >> 5 : 0;   // exact: mult of 32

    auto issueD = [&](int t) {
        const int nb = n0 + t * KT;
        float* slot = &sD[w][t & 1][0];
        const float* src = Db + (size_t)(nb + lg) * M + (w << 6) + (l15 << 2);
#pragma unroll
        for (int j = 0; j < 8; ++j)
            gload16(src + (size_t)(4 * j) * M, slot + j * 256);
    };

    float4 xreg[8];
    auto loadX = [&](int t) {
        const float* xp = &xb[(size_t)(n0 + t * KT + 8 * lg) * I + 4 * l15];
#pragma unroll
        for (int q = 0; q < 8; ++q)
            xreg[q] = *(const float4*)(xp + (size_t)q * I);
    };

    unsigned short* wX = sX[w];

    if (steps > 0) {
        issueD(0);
        if (steps > 1) issueD(1);
        loadX(0);

        for (int t = 0; t < steps; ++t) {
            const int p = t & 1;
            // ---- pack x(t) into wave-private cells
#pragma unroll
            for (int j = 0; j < 4; ++j) {
                uint4v cx;
#pragma unroll
                for (int e = 0; e < 4; ++e)
                    cx[e] = pk2bf(((const float*)&xreg[2 * e])[j],
                                  ((const float*)&xreg[2 * e + 1])[j]);
                *(uint4v*)&wX[((size_t)lg * 64 + MSW(4 * l15 + j)) * 8] = cx;
            }
            // ---- x fragments (octet lg)
            bf16x8 bfr[4];
#pragma unroll
            for (int v = 0; v < 4; ++v)
                bfr[v] = *(const bf16x8*)&wX[((size_t)lg * 64 + MSW(v * 16 + l15)) * 8];
            // ---- issue next x loads (in flight across gather+MFMA)
            if (t + 1 < steps) loadX(t + 1);
            // ---- gather D frags from fp32 slot p + cvt, then MFMA
            const float* slot = &sD[w][p][0];
#pragma unroll
            for (int sm = 0; sm < 4; ++sm) {
                float fr[8];
#pragma unroll
                for (int r = 0; r < 8; ++r)
                    fr[r] = slot[(8 * lg + r) * 64 + sm * 16 + l15];
                uint4v pk = {pk2bf(fr[0], fr[1]), pk2bf(fr[2], fr[3]),
                             pk2bf(fr[4], fr[5]), pk2bf(fr[6], fr[7])};
                bf16x8 afr = __builtin_bit_cast(bf16x8, pk);
#pragma unroll
                for (int v = 0; v < 4; ++v)
                    acc[sm][v] = __builtin_amdgcn_mfma_f32_16x16x32_bf16(
                        afr, bfr[v], acc[sm][v], 0, 0, 0);
            }
            // ---- refill slot p for step t+2 (after its reads, program order)
            if (t + 2 < steps) issueD(t + 2);
        }
    }

    // ---- store packed-bf16 partial: word c=sm*8+v*2+rp at w*2048+c*64+lane.
    // C-map (m89): acc[sm][v][r] is (m = w*64+sm*16+lg*4+r, i = v*16+l15);
    // pairs (r=2rp, 2rp+1) are adjacent m -> pk2bf packs (m0, m0+1).
    unsigned* pp = partial + ((size_t)s * B + b) * PW + (size_t)w * 2048 + lane;
#pragma unroll
    for (int sm = 0; sm < 4; ++sm)
#pragma unroll
        for (int v = 0; v < 4; ++v)
#pragma unroll
            for (int rp = 0; rp < 2; ++rp)
                pp[(sm * 8 + v * 2 + rp) * 64] =
                    pk2bf(acc[sm][v][2 * rp], acc[sm][v][2 * rp + 1]);
}

// ---------------- Reduce: dtx[b][m][i] = sum_s unpack(partial[s][b][word])
__global__ __launch_bounds__(256) void reduce_partials(const unsigned* __restrict__ partial,
                                                       float* __restrict__ dtx,
                                                       int nsplit) {
    const int bb = blockIdx.y;
    const int j = blockIdx.x * 256 + threadIdx.x;   // 0..PW-1
    // decode stage1's packed layout
    const int w    = j >> 11;
    const int rem  = j & 2047;
    const int c    = rem >> 6;
    const int lane = rem & 63;
    const int sm = c >> 3, v = (c >> 1) & 3, rp = c & 1;
    const int lg = lane >> 4, l15 = lane & 15;
    const int m0 = w * 64 + sm * 16 + lg * 4 + 2 * rp;
    const int i  = v * 16 + l15;

    const unsigned* p = partial + (size_t)bb * PW + j;
    float s0 = 0.f, s1 = 0.f;
#pragma unroll 4
    for (int s = 0; s < nsplit; ++s) {
        const unsigned word = p[(size_t)s * B * PW];
        s0 += __uint_as_float(word << 16);
        s1 += __uint_as_float(word & 0xFFFF0000u);
    }
    dtx[(size_t)bb * MI + (size_t)m0 * I + i]       = s0;
    dtx[(size_t)bb * MI + (size_t)(m0 + 1) * I + i] = s1;
}

// ---------------- Stage 2: ST[b][o][m] = bf16( (1/16) sum_i coeff[o][i][m]*dtx[b][m][i] )
__global__ __launch_bounds__(256) void stage2(const float* __restrict__ coeff,
                                              const float* __restrict__ dtx,
                                              unsigned short* __restrict__ ST) {
    const int g = blockIdx.x * 256 + threadIdx.x;
    const int b = g >> 14;            // O*M = 16384
    const int rem = g & 16383;
    const int o = rem >> 8;
    const int m = rem & 255;
    const float* dt = dtx + (size_t)b * MI + (size_t)m * I;
    const float* cf = coeff + (size_t)o * I * M + m;
    float acc = 0.f;
#pragma unroll 8
    for (int i = 0; i < I; ++i)
        acc = fmaf(cf[(size_t)i * M], dt[i], acc);
    ST[((size_t)b * O + o) * M + m] = f2bf(acc * 0.0625f);   // 1/sqrt(256)
}

// ---------------- Stage 3 (MFMA): out[b][n][o] = sum_m D[b,n,m] * S[b,m,o]
__global__ __launch_bounds__(256) void stage3(const float* __restrict__ Dg,
                                              const unsigned short* __restrict__ STg,
                                              float* __restrict__ outg) {
    const int b = blockIdx.y;
    const int n0 = blockIdx.x * 256;
    const int tid = threadIdx.x;
    const int lane = tid & 63;
    const int w = tid >> 6;

    __shared__ unsigned short sS[64 * SSS];   // 33 KB

    {
        const int o = tid >> 2, seg = (tid & 3) * 64;
        const unsigned short* src = STg + ((size_t)b * O + o) * M + seg;
        unsigned short* dst = &sS[o * SSS + seg];
#pragma unroll
        for (int c = 0; c < 8; ++c)
            *(uint4v*)&dst[c * 8] = *(const uint4v*)&src[c * 8];
    }

    f32x4 acc[4][4];
#pragma unroll
    for (int a = 0; a < 4; ++a)
#pragma unroll
        for (int v = 0; v < 4; ++v) acc[a][v] = (f32x4){0.f, 0.f, 0.f, 0.f};

    __syncthreads();

    const float* Db = Dg + (size_t)b * N * M;
    const int k8 = (lane >> 4) << 3;

#pragma unroll 1
    for (int ks = 0; ks < 8; ++ks) {
        const int kb = ks * 32 + k8;
        bf16x8 bfr[4];
#pragma unroll
        for (int v = 0; v < 4; ++v)
            bfr[v] = *(const bf16x8*)&sS[(v * 16 + (lane & 15)) * SSS + kb];
#pragma unroll
        for (int sn = 0; sn < 4; ++sn) {
            int n = n0 + w * 64 + sn * 16 + (lane & 15);
            n = min(n, N - 1);                       // tail clamp (stores guarded)
            const float* ap = Db + (size_t)n * M + kb;
            const float4 f0 = *(const float4*)ap;
            const float4 f1 = *(const float4*)(ap + 4);
            uint4v pk = {pk2bf(f0.x, f0.y), pk2bf(f0.z, f0.w),
                         pk2bf(f1.x, f1.y), pk2bf(f1.z, f1.w)};
            bf16x8 afr = __builtin_bit_cast(bf16x8, pk);
#pragma unroll
            for (int v = 0; v < 4; ++v)
                acc[sn][v] = __builtin_amdgcn_mfma_f32_16x16x32_bf16(
                    afr, bfr[v], acc[sn][v], 0, 0, 0);
        }
    }

#pragma unroll
    for (int sn = 0; sn < 4; ++sn)
#pragma unroll
        for (int v = 0; v < 4; ++v)
#pragma unroll
            for (int r = 0; r < 4; ++r) {
                const int n = n0 + w * 64 + sn * 16 + ((lane >> 4) << 2) + r;
                if (n < N)
                    outg[((size_t)b * N + n) * O + v * 16 + (lane & 15)] = acc[sn][v][r];
            }
}

extern "C" void kernel_launch(void* const* d_in, const int* in_sizes, int n_in,
                              void* d_out, int out_size, void* d_ws, size_t ws_size,
                              hipStream_t stream) {
    const float* Dg    = (const float*)d_in[0];
    const float* xg    = (const float*)d_in[1];
    const float* coeff = (const float*)d_in[2];
    float* outg = (float*)d_out;

    float* base = (float*)d_ws;
    float* dtx = base;                                   // B*MI floats   (512 KB)
    unsigned short* ST = (unsigned short*)(base + B * MI);  // B*O*M bf16 (256 KB)
    unsigned* partial = (unsigned*)(base + B * MI + B * MI / 2);  // split*B*PW u32

    // split-K from workspace; cap 64 -> chunk 320 (10 steps), split 63,
    // 504 four-wave blocks at 80KB LDS = 2 blocks/CU (r17 best-known config).
    const size_t fixed = (size_t)B * MI * 4 + (size_t)B * MI * 2;
    const size_t per   = (size_t)B * PW * sizeof(unsigned);   // 256 KB per slot
    int cap = 1;
    if (ws_size > fixed) {
        size_t c = (ws_size - fixed) / per;
        cap = (int)(c < 1 ? 1 : (c > 64 ? 64 : c));
    }
    int chunk = (((N + cap - 1) / cap) + KT - 1) & ~(KT - 1);
    int split = (N + chunk - 1) / chunk;   // blocks actually launched

    stage1<<<dim3(split, B), 256, 0, stream>>>(Dg, xg, partial, chunk);
    reduce_partials<<<dim3(PW / 256, B), 256, 0, stream>>>(partial, dtx, split);
    stage2<<<dim3((B * O * M) / 256), 256, 0, stream>>>(coeff, dtx, ST);
    stage3<<<dim3((N + 255) / 256, B), 256, 0, stream>>>(Dg, ST, outg);
}